// Round 12
// baseline (93.530 us; speedup 1.0000x reference)
//
#include <hip/hip_runtime.h>

// Conv4d implicit GEMM, v12 = v11 + one-phase register read-ahead (m201 pattern).
// wprep: weights f32 -> bf16 in MFMA-fragment order Wg[off][rt][ks][lane][8].
// sprep: input f32 -> bf16 half-slabs S[(b,w',x')][ks][rem=y'*18+z'][32 ci],
//        granule-swizzled: granule g of row rem at g ^ ((rem>>1)&3).
// main:  block = (b,w,x), 256 thr / 4 waves, wave owns y-tiles 4wv..4wv+3.
//        54 global phases u (tick p=u/3 over (kwx,ks-half), q=u%3 over kz). Per phase:
//          [stage A chunk for phase u+2 -> slot (u+2)%3; at q==1 stage B(p+1)]
//          [ds_read 12 A-frags + 6 B-frags for phase u+1 into reg bank (u+1)&1]
//          [sched_barrier]
//          [48 MFMA from bank u&1  -- no lgkm dependency on this phase's reads]
//          [vmcnt(0) + sched_barrier + s_barrier]
//        Reads and MFMA are dependency-decoupled by one phase -> LDS pipe (1728cyc/CU/
//        phase) runs under the MFMA pipe (1862cyc) instead of serializing (v11 measured
//        the sum). vmcnt(0) is a no-op wait here: every stage has a full phase in
//        flight. Loop unrolled x6 so all reg-bank/slot indices are static (rule #20).
//        LDS 78336B (A 3x12288 + B 2x20736) -> 2 blocks/CU; VGPR ~240 <= 256 (8 waves).

typedef __attribute__((ext_vector_type(8))) short bf16x8;
typedef __attribute__((ext_vector_type(4))) float f32x4;
typedef __attribute__((ext_vector_type(8))) unsigned short ushort8;
typedef unsigned short u16;
typedef unsigned int u32;

#define S_OFF_BYTES 663552u          // Wg = 81*4096 u16
#define WS_NEEDED   27537408u        // + 648 slabs * 41472 B

__device__ __forceinline__ u16 f2bf(float f) {
    u32 u = __float_as_uint(f);
    u += 0x7FFFu + ((u >> 16) & 1u);   // RNE
    return (u16)(u >> 16);
}

// ---------------- pre-pass 1: weights ----------------
__global__ __launch_bounds__(256) void wprep(const float* __restrict__ ker, u16* __restrict__ wg) {
    const int g = blockIdx.x * 256 + threadIdx.x;      // 0..41471
    const int l = g & 63, ks = (g >> 6) & 1, rt = (g >> 7) & 3, off = g >> 9;
    const int co  = rt * 16 + (l & 15);
    const int ci0 = ks * 32 + (l >> 4) * 8;
    const float* p = ker + (size_t)off * 4096 + co;
    ushort8 v;
#pragma unroll
    for (int e = 0; e < 8; ++e) v[e] = f2bf(p[(size_t)(ci0 + e) * 64]);
    *(ushort8*)(wg + (size_t)g * 8) = v;
}

// ---------------- pre-pass 2: input half-slabs (granule-swizzled) ----------------
__global__ __launch_bounds__(256) void sprep(const float* __restrict__ in, u16* __restrict__ s) {
    __shared__ u16 L[64 * 330];                        // [ci][rem padded]
    const int blk = blockIdx.x;                        // 648 = 2*18*18
    const int b = blk / 324, wx = blk - b * 324;
    const float* src = in + (size_t)b * 6718464 + (wx / 18) * 5832 + (wx % 18) * 324;
    const int t = threadIdx.x;
    for (int i = t; i < 5184; i += 256) {              // 64 ci * 81 float4
        const int ci = i / 81, j = i - ci * 81;
        float4 v = *(const float4*)(src + (size_t)ci * 104976 + j * 4);
        u32* q = (u32*)&L[ci * 330 + j * 4];
        q[0] = f2bf(v.x) | ((u32)f2bf(v.y) << 16);
        q[1] = f2bf(v.z) | ((u32)f2bf(v.w) << 16);
    }
    __syncthreads();
    u16* dst = s + (size_t)blk * 20736;                // [ks][rem][32 swizzled]
    for (int i = t; i < 2592; i += 256) {              // 2 ks * 324 rem * 4 granules
        const int ks = i / 1296, r4 = i - ks * 1296;
        const int rem = r4 >> 2, g = r4 & 3;
        ushort8 v;
#pragma unroll
        for (int e = 0; e < 8; ++e) v[e] = L[(ks * 32 + g * 8 + e) * 330 + rem];
        const int gp = g ^ ((rem >> 1) & 3);           // involution granule swizzle
        *(ushort8*)(dst + ks * 10368 + rem * 32 + gp * 8) = v;
    }
}

// ---------------- main ----------------
__global__ __launch_bounds__(256, 2)
void conv4d_main(const u16* __restrict__ wg, const u16* __restrict__ s, float* __restrict__ out) {
    __shared__ u16 A[3][6144];                         // 3 x 12288B A-chunk ring (slot = phase%3)
    __shared__ u16 Bq[2][10368];                       // 2 x 20736B B half-slab ring (tick&1)

    // bijective XCD swizzle (512 % 8 == 0)
    const int bid = blockIdx.x;
    const int bs  = (bid & 7) * 64 + (bid >> 3);
    const int b   = bs >> 8;
    const int w   = (bs >> 4) & 15;
    const int x   = bs & 15;

    const int t  = threadIdx.x, wv = t >> 6, l = t & 63;
    const int lg = l >> 4, ll = l & 15;

    f32x4 acc[4][4];
#pragma unroll
    for (int i = 0; i < 4; ++i)
#pragma unroll
        for (int j = 0; j < 4; ++j) acc[i][j] = (f32x4){0.f, 0.f, 0.f, 0.f};

    const u16* sb = s + (size_t)(b * 324 + w * 18 + x) * 20736;

    bf16x8 af[2][3][4];                                // double-banked fragment regs
    bf16x8 bb[2][6];

    // A chunk for (tick tk, kz KZ) -> slot KZ: 3 gll/wave (c = ky), wave stages rt=wv
#define STAGE_A(tk, KZ)                                                                  \
    do {                                                                                 \
        const int kwx_ = (tk) >> 1, ks2_ = (tk) & 1;                                     \
        _Pragma("unroll")                                                                \
        for (int c_ = 0; c_ < 3; ++c_) {                                                 \
            const u16* src_ = wg + (size_t)(kwx_ * 9 + c_ * 3 + (KZ)) * 4096             \
                              + wv * 1024 + ks2_ * 512 + l * 8;                          \
            __builtin_amdgcn_global_load_lds(                                            \
                (const __attribute__((address_space(1))) u32*)src_,                      \
                (__attribute__((address_space(3))) u32*)&A[KZ][c_ * 2048 + wv * 512 + l * 8], \
                16, 0, 0);                                                               \
        }                                                                                \
    } while (0)

    // B half-slab for tick h -> Bq[h&1]: 6 gll/wave (5 full + l<4 masked)
#define STAGE_B(h)                                                                       \
    do {                                                                                 \
        const int kwx_ = (h) >> 1, ks_ = (h) & 1;                                        \
        const int kw_ = kwx_ / 3, kx_ = kwx_ - kw_ * 3;                                  \
        const u16* src_ = sb + (size_t)(kw_ * 18 + kx_) * 20736 + ks_ * 10368;           \
        const int base_ = wv * 324;                                                      \
        _Pragma("unroll")                                                                \
        for (int k_ = 0; k_ < 5; ++k_) {                                                 \
            const int i_ = base_ + k_ * 64 + l;                                          \
            __builtin_amdgcn_global_load_lds(                                            \
                (const __attribute__((address_space(1))) u32*)(src_ + (size_t)i_ * 8),   \
                (__attribute__((address_space(3))) u32*)&Bq[(h) & 1][i_ * 8], 16, 0, 0); \
        }                                                                                \
        if (l < 4) {                                                                     \
            const int i_ = base_ + 320 + l;                                              \
            __builtin_amdgcn_global_load_lds(                                            \
                (const __attribute__((address_space(1))) u32*)(src_ + (size_t)i_ * 8),   \
                (__attribute__((address_space(3))) u32*)&Bq[(h) & 1][i_ * 8], 16, 0, 0); \
        }                                                                                \
    } while (0)

    // load fragment regs for phase UP into bank BK (QQ = UP%3, compile-time)
#define READ_REGS(BK, UP, QQ)                                                            \
    do {                                                                                 \
        const int tk_ = (UP) / 3;                                                        \
        const u16* Tb_ = Bq[tk_ & 1];                                                    \
        _Pragma("unroll")                                                                \
        for (int ky_ = 0; ky_ < 3; ++ky_)                                                \
            _Pragma("unroll")                                                            \
            for (int rt_ = 0; rt_ < 4; ++rt_)                                            \
                af[BK][ky_][rt_] = *(const bf16x8*)&A[QQ][ky_ * 2048 + rt_ * 512 + l * 8]; \
        _Pragma("unroll")                                                                \
        for (int j_ = 0; j_ < 6; ++j_) {                                                 \
            const int rem_ = (4 * wv + j_) * 18 + ll + (QQ);                             \
            bb[BK][j_] = *(const bf16x8*)&Tb_[rem_ * 32 + ((lg ^ ((rem_ >> 1) & 3)) << 3)]; \
        }                                                                                \
    } while (0)

#define MFMA_PHASE(BK)                                                                   \
    do {                                                                                 \
        __builtin_amdgcn_s_setprio(1);                                                   \
        _Pragma("unroll")                                                                \
        for (int ky_ = 0; ky_ < 3; ++ky_)                                                \
            _Pragma("unroll")                                                            \
            for (int ct_ = 0; ct_ < 4; ++ct_)                                            \
                _Pragma("unroll")                                                        \
                for (int rt_ = 0; rt_ < 4; ++rt_)                                        \
                    acc[rt_][ct_] = __builtin_amdgcn_mfma_f32_16x16x32_bf16(             \
                        af[BK][ky_][rt_], bb[BK][ct_ + ky_], acc[rt_][ct_], 0, 0, 0);    \
        __builtin_amdgcn_s_setprio(0);                                                   \
    } while (0)

    // prologue: chunks for phases 0,1; B tick 0; drain; read phase-0 regs into bank 0
    STAGE_A(0, 0);
    STAGE_A(0, 1);
    STAGE_B(0);
    asm volatile("s_waitcnt vmcnt(0)" ::: "memory");
    __builtin_amdgcn_sched_barrier(0);
    __builtin_amdgcn_s_barrier();
    READ_REGS(0, 0, 0);

    for (int u6 = 0; u6 < 54; u6 += 6) {
#pragma unroll
        for (int m = 0; m < 6; ++m) {
            const int u = u6 + m;
            if (u < 52) STAGE_A((u + 2) / 3, ((m + 2) % 3));
            if ((m % 3) == 1) {
                const int p_ = u / 3;
                if (p_ < 17) STAGE_B(p_ + 1);
            }
            if (u < 53) READ_REGS(((m + 1) & 1), (u + 1), ((m + 1) % 3));
            __builtin_amdgcn_sched_barrier(0);         // reads issued before MFMA cluster
            MFMA_PHASE((m & 1));
            if (u < 53) {
                asm volatile("s_waitcnt vmcnt(0)" ::: "memory");
                __builtin_amdgcn_sched_barrier(0);
                __builtin_amdgcn_s_barrier();
            }
        }
    }
#undef STAGE_A
#undef STAGE_B
#undef READ_REGS
#undef MFMA_PHASE

    float* ob = out + (size_t)b * 4194304 + (size_t)w * 4096 + (size_t)x * 256;
#pragma unroll
    for (int rt = 0; rt < 4; ++rt) {
        const int co0 = rt * 16 + 4 * lg;
#pragma unroll
        for (int ct = 0; ct < 4; ++ct) {
            const int base = (4 * wv + ct) * 16 + ll;
#pragma unroll
            for (int r = 0; r < 4; ++r)
                ob[(size_t)(co0 + r) * 65536 + base] = acc[rt][ct][r];
        }
    }
}

// ---------------- fallback (round-1 kernel, used if ws too small) ----------------
__global__ __launch_bounds__(512, 2)
void conv4d_mfma(const float* __restrict__ in, const float* __restrict__ ker,
                 float* __restrict__ out) {
    __shared__ unsigned short T[18 * 18 * 64];
    __shared__ unsigned short Wt[2][64 * 64];
    const int bx = blockIdx.x;
    const int b = bx >> 8, wsp = (bx >> 4) & 15, x = bx & 15;
    const int t = threadIdx.x, wv = t >> 6, l = t & 63;
    const int lg = l >> 4, ll = l & 15;
    const float* inb = in + (size_t)b * 6718464 + wsp * 5832 + x * 324;
    f32x4 acc[4][2];
#pragma unroll
    for (int i = 0; i < 4; ++i)
#pragma unroll
        for (int j = 0; j < 2; ++j) acc[i][j] = (f32x4){0.f, 0.f, 0.f, 0.f};
#pragma unroll
    for (int f0 = 0; f0 < 4096; f0 += 512) {
        const int f = f0 + t, ci = f >> 6, co = f & 63;
        Wt[0][co * 64 + ((((ci >> 3) ^ (co & 7)) << 3) | (ci & 7))] = f2bf(ker[f]);
    }
    for (int off = 0; off < 81; ++off) {
        const int sub = off % 9;
        if (sub == 0) {
            const int kw = off / 27, kx = (off / 9) % 3;
            const float* p = inb + kw * 5832 + kx * 324;
            for (int f = t; f < 18 * 18 * 64; f += 512) {
                const int ci = f / 324, rem = f - ci * 324, zp = rem % 18;
                T[rem * 64 + ((((ci >> 3) ^ (zp & 7)) << 3) | (ci & 7))] =
                    f2bf(p[(size_t)ci * 104976 + rem]);
            }
        }
        if (off + 1 < 81) {
            const float* p = ker + (off + 1) * 4096;
            unsigned short* wb = Wt[(off + 1) & 1];
#pragma unroll
            for (int f0 = 0; f0 < 4096; f0 += 512) {
                const int f = f0 + t, ci = f >> 6, co = f & 63;
                wb[co * 64 + ((((ci >> 3) ^ (co & 7)) << 3) | (ci & 7))] = f2bf(p[f]);
            }
        }
        if (sub == 0) __syncthreads();
        const int ky = sub / 3, kz = sub - ky * 3;
        const int zp = ll + kz, zs = zp & 7;
#pragma unroll
        for (int ks = 0; ks < 2; ++ks) {
            bf16x8 af[4];
#pragma unroll
            for (int rt = 0; rt < 4; ++rt)
                af[rt] = *(const bf16x8*)&Wt[off & 1][(rt * 16 + ll) * 64 + (((lg + 4 * ks) ^ (ll & 7)) << 3)];
#pragma unroll
            for (int ct = 0; ct < 2; ++ct) {
                const int rem = (2 * wv + ct + ky) * 18 + zp;
                const bf16x8 bfr = *(const bf16x8*)&T[rem * 64 + (((lg + 4 * ks) ^ zs) << 3)];
#pragma unroll
                for (int rt = 0; rt < 4; ++rt)
                    acc[rt][ct] = __builtin_amdgcn_mfma_f32_16x16x32_bf16(af[rt], bfr, acc[rt][ct], 0, 0, 0);
            }
        }
        __syncthreads();
    }
    float* ob = out + (size_t)b * 4194304 + wsp * 4096 + x * 256;
#pragma unroll
    for (int rt = 0; rt < 4; ++rt) {
        const int co0 = rt * 16 + 4 * lg;
#pragma unroll
        for (int ct = 0; ct < 2; ++ct) {
            const int base = (2 * wv + ct) * 16 + ll;
#pragma unroll
            for (int r = 0; r < 4; ++r)
                ob[(size_t)(co0 + r) * 65536 + base] = acc[rt][ct][r];
        }
    }
}

extern "C" void kernel_launch(void* const* d_in, const int* in_sizes, int n_in,
                              void* d_out, int out_size, void* d_ws, size_t ws_size,
                              hipStream_t stream) {
    const float* in  = (const float*)d_in[0];
    const float* ker = (const float*)d_in[1];
    float* out = (float*)d_out;
    if (ws_size >= (size_t)WS_NEEDED) {
        u16* wg = (u16*)d_ws;
        u16* s  = (u16*)((char*)d_ws + S_OFF_BYTES);
        wprep<<<dim3(162), dim3(256), 0, stream>>>(ker, wg);
        sprep<<<dim3(648), dim3(256), 0, stream>>>(in, s);
        conv4d_main<<<dim3(512), dim3(256), 0, stream>>>(wg, s, out);
    } else {
        conv4d_mfma<<<dim3(512), dim3(512), 0, stream>>>(in, ker, out);
    }
}

// Round 13
// 93.257 us; speedup vs baseline: 1.0029x; 1.0029x over previous
//
#include <hip/hip_runtime.h>

// Conv4d implicit GEMM, v13 = v12 + pinned occupancy (amdgpu_waves_per_eu(2,2)).
// Round-12 post-mortem: the double-banked read-ahead needs ~215 VGPR; launch_bounds'
// min-occupancy bound let the allocator shrink to 128 and SPILL (WRITE_SIZE +2.6MB)
// -> decoupling defeated. LDS (78.3KB) caps us at 2 blocks/CU anyway, so pin
// waves/EU to exactly 2 and let the allocator use the 256-VGPR tier.
//
// wprep: weights f32 -> bf16 in MFMA-fragment order Wg[off][rt][ks][lane][8].
// sprep: input f32 -> bf16 half-slabs S[(b,w',x')][ks][rem=y'*18+z'][32 ci],
//        granule-swizzled: granule g of row rem at g ^ ((rem>>1)&3).
// main:  block = (b,w,x), 256 thr / 4 waves, wave owns y-tiles 4wv..4wv+3.
//        54 phases u (tick p=u/3 over (kwx,ks), q=u%3 over kz). Per phase:
//          [stage A chunk(u+2) -> slot (u+2)%3; at q==1 stage B(p+1)]
//          [ds_read 12 A + 6 B fragments for phase u+1 into reg bank (u+1)&1]
//          [48 MFMA from bank u&1 -- zero lgkm dependency on this phase's reads]
//          [vmcnt(0) + sched_barrier + s_barrier]
//        LDS-read pipe (93K cyc/CU total) overlaps the MFMA pipe (100K cyc/CU)
//        instead of summing (v11 measured the sum).

typedef __attribute__((ext_vector_type(8))) short bf16x8;
typedef __attribute__((ext_vector_type(4))) float f32x4;
typedef __attribute__((ext_vector_type(8))) unsigned short ushort8;
typedef unsigned short u16;
typedef unsigned int u32;

#define S_OFF_BYTES 663552u          // Wg = 81*4096 u16
#define WS_NEEDED   27537408u        // + 648 slabs * 41472 B

__device__ __forceinline__ u16 f2bf(float f) {
    u32 u = __float_as_uint(f);
    u += 0x7FFFu + ((u >> 16) & 1u);   // RNE
    return (u16)(u >> 16);
}

// ---------------- pre-pass 1: weights ----------------
__global__ __launch_bounds__(256) void wprep(const float* __restrict__ ker, u16* __restrict__ wg) {
    const int g = blockIdx.x * 256 + threadIdx.x;      // 0..41471
    const int l = g & 63, ks = (g >> 6) & 1, rt = (g >> 7) & 3, off = g >> 9;
    const int co  = rt * 16 + (l & 15);
    const int ci0 = ks * 32 + (l >> 4) * 8;
    const float* p = ker + (size_t)off * 4096 + co;
    ushort8 v;
#pragma unroll
    for (int e = 0; e < 8; ++e) v[e] = f2bf(p[(size_t)(ci0 + e) * 64]);
    *(ushort8*)(wg + (size_t)g * 8) = v;
}

// ---------------- pre-pass 2: input half-slabs (granule-swizzled) ----------------
__global__ __launch_bounds__(256) void sprep(const float* __restrict__ in, u16* __restrict__ s) {
    __shared__ u16 L[64 * 330];                        // [ci][rem padded]
    const int blk = blockIdx.x;                        // 648 = 2*18*18
    const int b = blk / 324, wx = blk - b * 324;
    const float* src = in + (size_t)b * 6718464 + (wx / 18) * 5832 + (wx % 18) * 324;
    const int t = threadIdx.x;
    for (int i = t; i < 5184; i += 256) {              // 64 ci * 81 float4
        const int ci = i / 81, j = i - ci * 81;
        float4 v = *(const float4*)(src + (size_t)ci * 104976 + j * 4);
        u32* q = (u32*)&L[ci * 330 + j * 4];
        q[0] = f2bf(v.x) | ((u32)f2bf(v.y) << 16);
        q[1] = f2bf(v.z) | ((u32)f2bf(v.w) << 16);
    }
    __syncthreads();
    u16* dst = s + (size_t)blk * 20736;                // [ks][rem][32 swizzled]
    for (int i = t; i < 2592; i += 256) {              // 2 ks * 324 rem * 4 granules
        const int ks = i / 1296, r4 = i - ks * 1296;
        const int rem = r4 >> 2, g = r4 & 3;
        ushort8 v;
#pragma unroll
        for (int e = 0; e < 8; ++e) v[e] = L[(ks * 32 + g * 8 + e) * 330 + rem];
        const int gp = g ^ ((rem >> 1) & 3);           // involution granule swizzle
        *(ushort8*)(dst + ks * 10368 + rem * 32 + gp * 8) = v;
    }
}

// ---------------- main ----------------
__global__ __launch_bounds__(256)
__attribute__((amdgpu_waves_per_eu(2, 2)))
void conv4d_main(const u16* __restrict__ wg, const u16* __restrict__ s, float* __restrict__ out) {
    __shared__ u16 A[3][6144];                         // 3 x 12288B A-chunk ring (slot = phase%3)
    __shared__ u16 Bq[2][10368];                       // 2 x 20736B B half-slab ring (tick&1)

    // bijective XCD swizzle (512 % 8 == 0)
    const int bid = blockIdx.x;
    const int bs  = (bid & 7) * 64 + (bid >> 3);
    const int b   = bs >> 8;
    const int w   = (bs >> 4) & 15;
    const int x   = bs & 15;

    const int t  = threadIdx.x, wv = t >> 6, l = t & 63;
    const int lg = l >> 4, ll = l & 15;

    f32x4 acc[4][4];
#pragma unroll
    for (int i = 0; i < 4; ++i)
#pragma unroll
        for (int j = 0; j < 4; ++j) acc[i][j] = (f32x4){0.f, 0.f, 0.f, 0.f};

    const u16* sb = s + (size_t)(b * 324 + w * 18 + x) * 20736;

    bf16x8 af[2][3][4];                                // double-banked fragment regs
    bf16x8 bb[2][6];

    // A chunk for (tick tk, kz KZ) -> slot KZ: 3 gll/wave (c = ky), wave stages rt=wv
#define STAGE_A(tk, KZ)                                                                  \
    do {                                                                                 \
        const int kwx_ = (tk) >> 1, ks2_ = (tk) & 1;                                     \
        _Pragma("unroll")                                                                \
        for (int c_ = 0; c_ < 3; ++c_) {                                                 \
            const u16* src_ = wg + (size_t)(kwx_ * 9 + c_ * 3 + (KZ)) * 4096             \
                              + wv * 1024 + ks2_ * 512 + l * 8;                          \
            __builtin_amdgcn_global_load_lds(                                            \
                (const __attribute__((address_space(1))) u32*)src_,                      \
                (__attribute__((address_space(3))) u32*)&A[KZ][c_ * 2048 + wv * 512 + l * 8], \
                16, 0, 0);                                                               \
        }                                                                                \
    } while (0)

    // B half-slab for tick h -> Bq[h&1]: 6 gll/wave (5 full + l<4 masked)
#define STAGE_B(h)                                                                       \
    do {                                                                                 \
        const int kwx_ = (h) >> 1, ks_ = (h) & 1;                                        \
        const int kw_ = kwx_ / 3, kx_ = kwx_ - kw_ * 3;                                  \
        const u16* src_ = sb + (size_t)(kw_ * 18 + kx_) * 20736 + ks_ * 10368;           \
        const int base_ = wv * 324;                                                      \
        _Pragma("unroll")                                                                \
        for (int k_ = 0; k_ < 5; ++k_) {                                                 \
            const int i_ = base_ + k_ * 64 + l;                                          \
            __builtin_amdgcn_global_load_lds(                                            \
                (const __attribute__((address_space(1))) u32*)(src_ + (size_t)i_ * 8),   \
                (__attribute__((address_space(3))) u32*)&Bq[(h) & 1][i_ * 8], 16, 0, 0); \
        }                                                                                \
        if (l < 4) {                                                                     \
            const int i_ = base_ + 320 + l;                                              \
            __builtin_amdgcn_global_load_lds(                                            \
                (const __attribute__((address_space(1))) u32*)(src_ + (size_t)i_ * 8),   \
                (__attribute__((address_space(3))) u32*)&Bq[(h) & 1][i_ * 8], 16, 0, 0); \
        }                                                                                \
    } while (0)

    // load fragment regs for phase UP into bank BK (QQ = UP%3, compile-time)
#define READ_REGS(BK, UP, QQ)                                                            \
    do {                                                                                 \
        const int tk_ = (UP) / 3;                                                        \
        const u16* Tb_ = Bq[tk_ & 1];                                                    \
        _Pragma("unroll")                                                                \
        for (int ky_ = 0; ky_ < 3; ++ky_)                                                \
            _Pragma("unroll")                                                            \
            for (int rt_ = 0; rt_ < 4; ++rt_)                                            \
                af[BK][ky_][rt_] = *(const bf16x8*)&A[QQ][ky_ * 2048 + rt_ * 512 + l * 8]; \
        _Pragma("unroll")                                                                \
        for (int j_ = 0; j_ < 6; ++j_) {                                                 \
            const int rem_ = (4 * wv + j_) * 18 + ll + (QQ);                             \
            bb[BK][j_] = *(const bf16x8*)&Tb_[rem_ * 32 + ((lg ^ ((rem_ >> 1) & 3)) << 3)]; \
        }                                                                                \
    } while (0)

#define MFMA_PHASE(BK)                                                                   \
    do {                                                                                 \
        __builtin_amdgcn_s_setprio(1);                                                   \
        _Pragma("unroll")                                                                \
        for (int ky_ = 0; ky_ < 3; ++ky_)                                                \
            _Pragma("unroll")                                                            \
            for (int ct_ = 0; ct_ < 4; ++ct_)                                            \
                _Pragma("unroll")                                                        \
                for (int rt_ = 0; rt_ < 4; ++rt_)                                        \
                    acc[rt_][ct_] = __builtin_amdgcn_mfma_f32_16x16x32_bf16(             \
                        af[BK][ky_][rt_], bb[BK][ct_ + ky_], acc[rt_][ct_], 0, 0, 0);    \
        __builtin_amdgcn_s_setprio(0);                                                   \
    } while (0)

    // prologue: chunks for phases 0,1; B tick 0; drain; read phase-0 regs into bank 0
    STAGE_A(0, 0);
    STAGE_A(0, 1);
    STAGE_B(0);
    asm volatile("s_waitcnt vmcnt(0)" ::: "memory");
    __builtin_amdgcn_sched_barrier(0);
    __builtin_amdgcn_s_barrier();
    READ_REGS(0, 0, 0);

    for (int u6 = 0; u6 < 54; u6 += 6) {
#pragma unroll
        for (int m = 0; m < 6; ++m) {
            const int u = u6 + m;
            if (u < 52) STAGE_A((u + 2) / 3, ((m + 2) % 3));
            if ((m % 3) == 1) {
                const int p_ = u / 3;
                if (p_ < 17) STAGE_B(p_ + 1);
            }
            if (u < 53) READ_REGS(((m + 1) & 1), (u + 1), ((m + 1) % 3));
            __builtin_amdgcn_sched_barrier(0);         // reads issued before MFMA cluster
            MFMA_PHASE((m & 1));
            if (u < 53) {
                asm volatile("s_waitcnt vmcnt(0)" ::: "memory");
                __builtin_amdgcn_sched_barrier(0);
                __builtin_amdgcn_s_barrier();
            }
        }
    }
#undef STAGE_A
#undef STAGE_B
#undef READ_REGS
#undef MFMA_PHASE

    float* ob = out + (size_t)b * 4194304 + (size_t)w * 4096 + (size_t)x * 256;
#pragma unroll
    for (int rt = 0; rt < 4; ++rt) {
        const int co0 = rt * 16 + 4 * lg;
#pragma unroll
        for (int ct = 0; ct < 4; ++ct) {
            const int base = (4 * wv + ct) * 16 + ll;
#pragma unroll
            for (int r = 0; r < 4; ++r)
                ob[(size_t)(co0 + r) * 65536 + base] = acc[rt][ct][r];
        }
    }
}

// ---------------- fallback (round-1 kernel, used if ws too small) ----------------
__global__ __launch_bounds__(512, 2)
void conv4d_mfma(const float* __restrict__ in, const float* __restrict__ ker,
                 float* __restrict__ out) {
    __shared__ unsigned short T[18 * 18 * 64];
    __shared__ unsigned short Wt[2][64 * 64];
    const int bx = blockIdx.x;
    const int b = bx >> 8, wsp = (bx >> 4) & 15, x = bx & 15;
    const int t = threadIdx.x, wv = t >> 6, l = t & 63;
    const int lg = l >> 4, ll = l & 15;
    const float* inb = in + (size_t)b * 6718464 + wsp * 5832 + x * 324;
    f32x4 acc[4][2];
#pragma unroll
    for (int i = 0; i < 4; ++i)
#pragma unroll
        for (int j = 0; j < 2; ++j) acc[i][j] = (f32x4){0.f, 0.f, 0.f, 0.f};
#pragma unroll
    for (int f0 = 0; f0 < 4096; f0 += 512) {
        const int f = f0 + t, ci = f >> 6, co = f & 63;
        Wt[0][co * 64 + ((((ci >> 3) ^ (co & 7)) << 3) | (ci & 7))] = f2bf(ker[f]);
    }
    for (int off = 0; off < 81; ++off) {
        const int sub = off % 9;
        if (sub == 0) {
            const int kw = off / 27, kx = (off / 9) % 3;
            const float* p = inb + kw * 5832 + kx * 324;
            for (int f = t; f < 18 * 18 * 64; f += 512) {
                const int ci = f / 324, rem = f - ci * 324, zp = rem % 18;
                T[rem * 64 + ((((ci >> 3) ^ (zp & 7)) << 3) | (ci & 7))] =
                    f2bf(p[(size_t)ci * 104976 + rem]);
            }
        }
        if (off + 1 < 81) {
            const float* p = ker + (off + 1) * 4096;
            unsigned short* wb = Wt[(off + 1) & 1];
#pragma unroll
            for (int f0 = 0; f0 < 4096; f0 += 512) {
                const int f = f0 + t, ci = f >> 6, co = f & 63;
                wb[co * 64 + ((((ci >> 3) ^ (co & 7)) << 3) | (ci & 7))] = f2bf(p[f]);
            }
        }
        if (sub == 0) __syncthreads();
        const int ky = sub / 3, kz = sub - ky * 3;
        const int zp = ll + kz, zs = zp & 7;
#pragma unroll
        for (int ks = 0; ks < 2; ++ks) {
            bf16x8 af[4];
#pragma unroll
            for (int rt = 0; rt < 4; ++rt)
                af[rt] = *(const bf16x8*)&Wt[off & 1][(rt * 16 + ll) * 64 + (((lg + 4 * ks) ^ (ll & 7)) << 3)];
#pragma unroll
            for (int ct = 0; ct < 2; ++ct) {
                const int rem = (2 * wv + ct + ky) * 18 + zp;
                const bf16x8 bfr = *(const bf16x8*)&T[rem * 64 + (((lg + 4 * ks) ^ zs) << 3)];
#pragma unroll
                for (int rt = 0; rt < 4; ++rt)
                    acc[rt][ct] = __builtin_amdgcn_mfma_f32_16x16x32_bf16(af[rt], bfr, acc[rt][ct], 0, 0, 0);
            }
        }
        __syncthreads();
    }
    float* ob = out + (size_t)b * 4194304 + wsp * 4096 + x * 256;
#pragma unroll
    for (int rt = 0; rt < 4; ++rt) {
        const int co0 = rt * 16 + 4 * lg;
#pragma unroll
        for (int ct = 0; ct < 2; ++ct) {
            const int base = (2 * wv + ct) * 16 + ll;
#pragma unroll
            for (int r = 0; r < 4; ++r)
                ob[(size_t)(co0 + r) * 65536 + base] = acc[rt][ct][r];
        }
    }
}

extern "C" void kernel_launch(void* const* d_in, const int* in_sizes, int n_in,
                              void* d_out, int out_size, void* d_ws, size_t ws_size,
                              hipStream_t stream) {
    const float* in  = (const float*)d_in[0];
    const float* ker = (const float*)d_in[1];
    float* out = (float*)d_out;
    if (ws_size >= (size_t)WS_NEEDED) {
        u16* wg = (u16*)d_ws;
        u16* s  = (u16*)((char*)d_ws + S_OFF_BYTES);
        wprep<<<dim3(162), dim3(256), 0, stream>>>(ker, wg);
        sprep<<<dim3(648), dim3(256), 0, stream>>>(in, s);
        conv4d_main<<<dim3(512), dim3(256), 0, stream>>>(wg, s, out);
    } else {
        conv4d_mfma<<<dim3(512), dim3(512), 0, stream>>>(in, ker, out);
    }
}

// Round 14
// 92.184 us; speedup vs baseline: 1.0146x; 1.0116x over previous
//
#include <hip/hip_runtime.h>

// Conv4d implicit GEMM, v14 = decoupled phases with low-pressure register pipeline.
// wprep: weights f32 -> bf16 in MFMA-fragment order Wg[off][rt][ks][lane][8].
// sprep: input f32 -> bf16 half-slabs S[(b,w',x')][ks][rem=y'*18+z'][32 ci],
//        granule-swizzled: granule g of row rem at g ^ ((rem>>1)&3).
// main:  block = (b,w,x), 256 thr / 4 waves, wave owns y-tiles 4wv..4wv+3.
//        54 phases u (tick p=u/3 over (kwx,ks), q=u%3 over kz). Schedule per phase:
//          STAGE_A(u+2 -> slot (u+2)%3)   [3 gll/wave]
//          q==0: STAGE_B(p+1)             [6 gll/wave]  (q0 so it retires end-of-q1,
//                                          read-ahead at q2 is all-waves safe)
//          READ_A ky0 (JIT) ; READ_B(next phase) ; READ_A ky1   [lgkm in-flight]
//          MFMA ky0 (waits only ky0 frags) ; READ_A ky2 ; MFMA ky1 ; MFMA ky2
//          counted s_waitcnt vmcnt(9|3|0) + sched_barrier + s_barrier (never drains
//          the just-issued stages; a slot staged at v is first read at v+2, i.e.
//          after every wave's end-of-(v+1) wait retired it).
//        Pressure ~160 VGPR (acc 64 + bb[2][6] 48 + af[2][4] 32 + addr);
//        __launch_bounds__(256,1) lifts the 128-reg tier that spilled v12/v13.
//        LDS 78336B (A 3x12288 + B 2x20736) -> 2 blocks/CU.

typedef __attribute__((ext_vector_type(8))) short bf16x8;
typedef __attribute__((ext_vector_type(4))) float f32x4;
typedef __attribute__((ext_vector_type(8))) unsigned short ushort8;
typedef unsigned short u16;
typedef unsigned int u32;

#define S_OFF_BYTES 663552u          // Wg = 81*4096 u16
#define WS_NEEDED   27537408u        // + 648 slabs * 41472 B

__device__ __forceinline__ u16 f2bf(float f) {
    u32 u = __float_as_uint(f);
    u += 0x7FFFu + ((u >> 16) & 1u);   // RNE
    return (u16)(u >> 16);
}

// ---------------- pre-pass 1: weights ----------------
__global__ __launch_bounds__(256) void wprep(const float* __restrict__ ker, u16* __restrict__ wg) {
    const int g = blockIdx.x * 256 + threadIdx.x;      // 0..41471
    const int l = g & 63, ks = (g >> 6) & 1, rt = (g >> 7) & 3, off = g >> 9;
    const int co  = rt * 16 + (l & 15);
    const int ci0 = ks * 32 + (l >> 4) * 8;
    const float* p = ker + (size_t)off * 4096 + co;
    ushort8 v;
#pragma unroll
    for (int e = 0; e < 8; ++e) v[e] = f2bf(p[(size_t)(ci0 + e) * 64]);
    *(ushort8*)(wg + (size_t)g * 8) = v;
}

// ---------------- pre-pass 2: input half-slabs (granule-swizzled) ----------------
__global__ __launch_bounds__(256) void sprep(const float* __restrict__ in, u16* __restrict__ s) {
    __shared__ u16 L[64 * 330];                        // [ci][rem padded]
    const int blk = blockIdx.x;                        // 648 = 2*18*18
    const int b = blk / 324, wx = blk - b * 324;
    const float* src = in + (size_t)b * 6718464 + (wx / 18) * 5832 + (wx % 18) * 324;
    const int t = threadIdx.x;
    for (int i = t; i < 5184; i += 256) {              // 64 ci * 81 float4
        const int ci = i / 81, j = i - ci * 81;
        float4 v = *(const float4*)(src + (size_t)ci * 104976 + j * 4);
        u32* q = (u32*)&L[ci * 330 + j * 4];
        q[0] = f2bf(v.x) | ((u32)f2bf(v.y) << 16);
        q[1] = f2bf(v.z) | ((u32)f2bf(v.w) << 16);
    }
    __syncthreads();
    u16* dst = s + (size_t)blk * 20736;                // [ks][rem][32 swizzled]
    for (int i = t; i < 2592; i += 256) {              // 2 ks * 324 rem * 4 granules
        const int ks = i / 1296, r4 = i - ks * 1296;
        const int rem = r4 >> 2, g = r4 & 3;
        ushort8 v;
#pragma unroll
        for (int e = 0; e < 8; ++e) v[e] = L[(ks * 32 + g * 8 + e) * 330 + rem];
        const int gp = g ^ ((rem >> 1) & 3);           // involution granule swizzle
        *(ushort8*)(dst + ks * 10368 + rem * 32 + gp * 8) = v;
    }
}

// ---------------- main ----------------
__global__ __launch_bounds__(256, 1)
void conv4d_main(const u16* __restrict__ wg, const u16* __restrict__ s, float* __restrict__ out) {
    __shared__ u16 A[3][6144];                         // 3 x 12288B A-chunk ring (slot = phase%3)
    __shared__ u16 Bq[2][10368];                       // 2 x 20736B B half-slab ring (tick&1)

    // bijective XCD swizzle (512 % 8 == 0)
    const int bid = blockIdx.x;
    const int bs  = (bid & 7) * 64 + (bid >> 3);
    const int b   = bs >> 8;
    const int w   = (bs >> 4) & 15;
    const int x   = bs & 15;

    const int t  = threadIdx.x, wv = t >> 6, l = t & 63;
    const int lg = l >> 4, ll = l & 15;

    f32x4 acc[4][4];
#pragma unroll
    for (int i = 0; i < 4; ++i)
#pragma unroll
        for (int j = 0; j < 4; ++j) acc[i][j] = (f32x4){0.f, 0.f, 0.f, 0.f};

    const u16* sb = s + (size_t)(b * 324 + w * 18 + x) * 20736;

    bf16x8 af[2][4];                                   // within-phase A ping-pong
    bf16x8 bb[2][6];                                   // phase-banked B rows

#define STAGE_A(tk, KZ)                                                                  \
    do {                                                                                 \
        const int kwx_ = (tk) >> 1, ks2_ = (tk) & 1;                                     \
        _Pragma("unroll")                                                                \
        for (int c_ = 0; c_ < 3; ++c_) {                                                 \
            const u16* src_ = wg + (size_t)(kwx_ * 9 + c_ * 3 + (KZ)) * 4096             \
                              + wv * 1024 + ks2_ * 512 + l * 8;                          \
            __builtin_amdgcn_global_load_lds(                                            \
                (const __attribute__((address_space(1))) u32*)src_,                      \
                (__attribute__((address_space(3))) u32*)&A[KZ][c_ * 2048 + wv * 512 + l * 8], \
                16, 0, 0);                                                               \
        }                                                                                \
    } while (0)

#define STAGE_B(h)                                                                       \
    do {                                                                                 \
        const int kwx_ = (h) >> 1, ks_ = (h) & 1;                                        \
        const int kw_ = kwx_ / 3, kx_ = kwx_ - kw_ * 3;                                  \
        const u16* src_ = sb + (size_t)(kw_ * 18 + kx_) * 20736 + ks_ * 10368;           \
        const int base_ = wv * 324;                                                      \
        _Pragma("unroll")                                                                \
        for (int k_ = 0; k_ < 5; ++k_) {                                                 \
            const int i_ = base_ + k_ * 64 + l;                                          \
            __builtin_amdgcn_global_load_lds(                                            \
                (const __attribute__((address_space(1))) u32*)(src_ + (size_t)i_ * 8),   \
                (__attribute__((address_space(3))) u32*)&Bq[(h) & 1][i_ * 8], 16, 0, 0); \
        }                                                                                \
        if (l < 4) {                                                                     \
            const int i_ = base_ + 320 + l;                                              \
            __builtin_amdgcn_global_load_lds(                                            \
                (const __attribute__((address_space(1))) u32*)(src_ + (size_t)i_ * 8),   \
                (__attribute__((address_space(3))) u32*)&Bq[(h) & 1][i_ * 8], 16, 0, 0); \
        }                                                                                \
    } while (0)

#define READ_A(BK, SLOT, KY)                                                             \
    do {                                                                                 \
        _Pragma("unroll")                                                                \
        for (int rt_ = 0; rt_ < 4; ++rt_)                                                \
            af[BK][rt_] = *(const bf16x8*)&A[SLOT][(KY) * 2048 + rt_ * 512 + l * 8];     \
    } while (0)

#define READ_B(BK, TKPAR, QQ)                                                            \
    do {                                                                                 \
        const u16* Tb_ = Bq[TKPAR];                                                      \
        _Pragma("unroll")                                                                \
        for (int j_ = 0; j_ < 6; ++j_) {                                                 \
            const int rem_ = (4 * wv + j_) * 18 + ll + (QQ);                             \
            bb[BK][j_] = *(const bf16x8*)&Tb_[rem_ * 32 + ((lg ^ ((rem_ >> 1) & 3)) << 3)]; \
        }                                                                                \
    } while (0)

#define MFMA16(ABK, BBK, KY)                                                             \
    do {                                                                                 \
        __builtin_amdgcn_s_setprio(1);                                                   \
        _Pragma("unroll")                                                                \
        for (int ct_ = 0; ct_ < 4; ++ct_)                                                \
            _Pragma("unroll")                                                            \
            for (int rt_ = 0; rt_ < 4; ++rt_)                                            \
                acc[rt_][ct_] = __builtin_amdgcn_mfma_f32_16x16x32_bf16(                 \
                    af[ABK][rt_], bb[BBK][ct_ + (KY)], acc[rt_][ct_], 0, 0, 0);          \
        __builtin_amdgcn_s_setprio(0);                                                   \
    } while (0)

#define WAITBAR(N)                                                                       \
    do {                                                                                 \
        asm volatile("s_waitcnt vmcnt(" #N ")" ::: "memory");                            \
        __builtin_amdgcn_sched_barrier(0);                                               \
        __builtin_amdgcn_s_barrier();                                                    \
    } while (0)

    // prologue: A slots for phases 0,1; B(0); full drain; bank B(phase 0)
    STAGE_A(0, 0);
    STAGE_A(0, 1);
    STAGE_B(0);
    WAITBAR(0);
    READ_B(0, 0, 0);

    for (int u6 = 0; u6 < 54; u6 += 6) {
#pragma unroll
        for (int m = 0; m < 6; ++m) {
            const int u = u6 + m;
            const int cb = m & 1;                      // B bank of this phase (static)
            if (u < 52) STAGE_A((u + 2) / 3, (m + 2) % 3);
            if (m % 3 == 0 && u < 51) STAGE_B(u / 3 + 1);
            READ_A(0, m % 3, 0);                       // ky0 JIT (slot staged u-2: safe)
            if (u < 53) READ_B(cb ^ 1, (((m + 1) / 3) & 1), (m + 1) % 3);
            READ_A(1, m % 3, 1);                       // ky1 ahead, flies under ky0 MFMA
            __builtin_amdgcn_sched_barrier(0);
            MFMA16(0, cb, 0);                          // waits only ky0 frags (oldest)
            READ_A(0, m % 3, 2);                       // ky2 ahead (bank0 free again)
            __builtin_amdgcn_sched_barrier(0);
            MFMA16(1, cb, 1);
            __builtin_amdgcn_sched_barrier(0);
            MFMA16(0, cb, 2);
            if (u < 53) {
                if (m % 3 == 0) { if (u < 51) WAITBAR(9); else WAITBAR(3); }
                else            { if (u < 52) WAITBAR(3); else WAITBAR(0); }
            }
        }
    }
#undef STAGE_A
#undef STAGE_B
#undef READ_A
#undef READ_B
#undef MFMA16
#undef WAITBAR

    float* ob = out + (size_t)b * 4194304 + (size_t)w * 4096 + (size_t)x * 256;
#pragma unroll
    for (int rt = 0; rt < 4; ++rt) {
        const int co0 = rt * 16 + 4 * lg;
#pragma unroll
        for (int ct = 0; ct < 4; ++ct) {
            const int base = (4 * wv + ct) * 16 + ll;
#pragma unroll
            for (int r = 0; r < 4; ++r)
                ob[(size_t)(co0 + r) * 65536 + base] = acc[rt][ct][r];
        }
    }
}

// ---------------- fallback (round-1 kernel, used if ws too small) ----------------
__global__ __launch_bounds__(512, 2)
void conv4d_mfma(const float* __restrict__ in, const float* __restrict__ ker,
                 float* __restrict__ out) {
    __shared__ unsigned short T[18 * 18 * 64];
    __shared__ unsigned short Wt[2][64 * 64];
    const int bx = blockIdx.x;
    const int b = bx >> 8, wsp = (bx >> 4) & 15, x = bx & 15;
    const int t = threadIdx.x, wv = t >> 6, l = t & 63;
    const int lg = l >> 4, ll = l & 15;
    const float* inb = in + (size_t)b * 6718464 + wsp * 5832 + x * 324;
    f32x4 acc[4][2];
#pragma unroll
    for (int i = 0; i < 4; ++i)
#pragma unroll
        for (int j = 0; j < 2; ++j) acc[i][j] = (f32x4){0.f, 0.f, 0.f, 0.f};
#pragma unroll
    for (int f0 = 0; f0 < 4096; f0 += 512) {
        const int f = f0 + t, ci = f >> 6, co = f & 63;
        Wt[0][co * 64 + ((((ci >> 3) ^ (co & 7)) << 3) | (ci & 7))] = f2bf(ker[f]);
    }
    for (int off = 0; off < 81; ++off) {
        const int sub = off % 9;
        if (sub == 0) {
            const int kw = off / 27, kx = (off / 9) % 3;
            const float* p = inb + kw * 5832 + kx * 324;
            for (int f = t; f < 18 * 18 * 64; f += 512) {
                const int ci = f / 324, rem = f - ci * 324, zp = rem % 18;
                T[rem * 64 + ((((ci >> 3) ^ (zp & 7)) << 3) | (ci & 7))] =
                    f2bf(p[(size_t)ci * 104976 + rem]);
            }
        }
        if (off + 1 < 81) {
            const float* p = ker + (off + 1) * 4096;
            unsigned short* wb = Wt[(off + 1) & 1];
#pragma unroll
            for (int f0 = 0; f0 < 4096; f0 += 512) {
                const int f = f0 + t, ci = f >> 6, co = f & 63;
                wb[co * 64 + ((((ci >> 3) ^ (co & 7)) << 3) | (ci & 7))] = f2bf(p[f]);
            }
        }
        if (sub == 0) __syncthreads();
        const int ky = sub / 3, kz = sub - ky * 3;
        const int zp = ll + kz, zs = zp & 7;
#pragma unroll
        for (int ks = 0; ks < 2; ++ks) {
            bf16x8 af[4];
#pragma unroll
            for (int rt = 0; rt < 4; ++rt)
                af[rt] = *(const bf16x8*)&Wt[off & 1][(rt * 16 + ll) * 64 + (((lg + 4 * ks) ^ (ll & 7)) << 3)];
#pragma unroll
            for (int ct = 0; ct < 2; ++ct) {
                const int rem = (2 * wv + ct + ky) * 18 + zp;
                const bf16x8 bfr = *(const bf16x8*)&T[rem * 64 + (((lg + 4 * ks) ^ zs) << 3)];
#pragma unroll
                for (int rt = 0; rt < 4; ++rt)
                    acc[rt][ct] = __builtin_amdgcn_mfma_f32_16x16x32_bf16(af[rt], bfr, acc[rt][ct], 0, 0, 0);
            }
        }
        __syncthreads();
    }
    float* ob = out + (size_t)b * 4194304 + wsp * 4096 + x * 256;
#pragma unroll
    for (int rt = 0; rt < 4; ++rt) {
        const int co0 = rt * 16 + 4 * lg;
#pragma unroll
        for (int ct = 0; ct < 2; ++ct) {
            const int base = (2 * wv + ct) * 16 + ll;
#pragma unroll
            for (int r = 0; r < 4; ++r)
                ob[(size_t)(co0 + r) * 65536 + base] = acc[rt][ct][r];
        }
    }
}

extern "C" void kernel_launch(void* const* d_in, const int* in_sizes, int n_in,
                              void* d_out, int out_size, void* d_ws, size_t ws_size,
                              hipStream_t stream) {
    const float* in  = (const float*)d_in[0];
    const float* ker = (const float*)d_in[1];
    float* out = (float*)d_out;
    if (ws_size >= (size_t)WS_NEEDED) {
        u16* wg = (u16*)d_ws;
        u16* s  = (u16*)((char*)d_ws + S_OFF_BYTES);
        wprep<<<dim3(162), dim3(256), 0, stream>>>(ker, wg);
        sprep<<<dim3(648), dim3(256), 0, stream>>>(in, s);
        conv4d_main<<<dim3(512), dim3(256), 0, stream>>>(wg, s, out);
    } else {
        conv4d_mfma<<<dim3(512), dim3(512), 0, stream>>>(in, ker, out);
    }
}